// Round 4
// baseline (132.230 us; speedup 1.0000x reference)
//
#include <hip/hip_runtime.h>
#include <math.h>

// Problem constants (match reference)
#define NB 16       // batch
#define NL 512      // rows per batch
#define NS 512      // samples per row
#define NE 3000     // ecdf grid points (3*N_REF)
#define NR 1000     // ref points
#define NROWS (NB * NL)
#define NBIN 512    // counting-sort bins (avg 1 sample/bin)
#define WCAP 2048   // ecdf window capacity (typical W ~ 1100)

__device__ __forceinline__ float fast_rcp(float x) { return __builtin_amdgcn_rcpf(x); }

__global__ __launch_bounds__(256) void lcot_row_kernel(
    const float* __restrict__ x1, const float* __restrict__ x2,
    const float* __restrict__ ref, float* __restrict__ row_out)
{
    // phase 1 layout: sorted[512] | hist[512] | prefix[513]   (6148 B)
    // phase 2 layout: cnt[WCAP]                               (8192 B)
    __shared__ unsigned char s_pool[WCAP * 4];
    __shared__ float    s_ecdfw[WCAP];      // windowed ecdf values
    __shared__ float2   s_params[NBIN];     // (x0, slope) per sample interval, 511 used
    __shared__ float    s_wredf[4];
    __shared__ unsigned s_wredu[4];
    __shared__ unsigned s_segcnt[3];

    float*    s_sorted = (float*)s_pool;              // [512]
    unsigned* s_hist   = (unsigned*)(s_pool + 2048);  // [512]
    unsigned* s_prefix = (unsigned*)(s_pool + 4096);  // [513]
    unsigned* s_cnt    = (unsigned*)s_pool;           // [WCAP], phase 2

    const int tid  = threadIdx.x;
    const int lane = tid & 63;
    const int wave = tid >> 6;
    const int row  = blockIdx.x;
    const float inv_n   = 1.0f / 512.0f;            // exact
    const float step    = (float)(3.0 / 2999.0);    // linspace(-1,2,3000) spacing
    const float invstep = 2999.0f / 3.0f;

    // preload this thread's 4 query refs once (threads 250..255 idle in inverse)
    const int j0 = tid * 4;
    float rj0 = 0.f, rj1 = 0.f, rj2 = 0.f, rj3 = 0.f;
    if (j0 < NR) {
        float4 r4 = ((const float4*)ref)[tid];
        rj0 = r4.x; rj1 = r4.y; rj2 = r4.z; rj3 = r4.w;
    }
    float e1r0 = 0.f, e1r1 = 0.f, e1r2 = 0.f, e1r3 = 0.f;   // e1 kept in registers

    float acc = 0.0f;

    for (int inp = 0; inp < 2; ++inp) {
        const float* src = (inp == 0 ? x1 : x2) + (size_t)row * NS;
        float v0 = src[tid];
        float v1 = src[tid + 256];

        // ---- zero histogram + alpha wave-partials ----
        s_hist[tid] = 0u;
        s_hist[tid + 256] = 0u;
        float s = v0 + v1;
        #pragma unroll
        for (int o = 32; o > 0; o >>= 1) s += __shfl_down(s, o, 64);
        if (lane == 0) s_wredf[wave] = s;
        __syncthreads();                                   // (A)

        // ---- histogram ----
        int b0 = min((int)(v0 * 512.0f), NBIN - 1);
        int b1 = min((int)(v1 * 512.0f), NBIN - 1);
        atomicAdd(&s_hist[b0], 1u);
        atomicAdd(&s_hist[b1], 1u);
        __syncthreads();                                   // (B)

        float alpha = (s_wredf[0] + s_wredf[1] + s_wredf[2] + s_wredf[3]) * inv_n - 0.5f;

        // ---- exclusive prefix over 512 bins (2 consecutive bins / thread) ----
        unsigned h0 = s_hist[2 * tid];
        unsigned h1 = s_hist[2 * tid + 1];
        unsigned ls = h0 + h1;
        unsigned sc0 = ls;                                 // wave inclusive scan
        #pragma unroll
        for (int o = 1; o < 64; o <<= 1) {
            unsigned t2 = __shfl_up(sc0, o, 64);
            if (lane >= o) sc0 += t2;
        }
        if (lane == 63) s_wredu[wave] = sc0;
        __syncthreads();                                   // (C)
        unsigned wbase0 = 0;
        for (int w = 0; w < 4; ++w) if (w < wave) wbase0 += s_wredu[w];
        unsigned base = wbase0 + sc0 - ls;                 // exclusive base for bin 2*tid
        s_prefix[2 * tid]     = base;
        s_prefix[2 * tid + 1] = base + h0;
        s_hist[2 * tid]       = base;                      // scatter cursors
        s_hist[2 * tid + 1]   = base + h0;
        if (tid == 255) s_prefix[NBIN] = (unsigned)NS;
        __syncthreads();                                   // (D)

        // ---- scatter ----
        unsigned p0 = atomicAdd(&s_hist[b0], 1u);
        s_sorted[p0] = v0;
        unsigned p1 = atomicAdd(&s_hist[b1], 1u);
        s_sorted[p1] = v1;
        __syncthreads();                                   // (E)

        // ---- per-bin insertion sort (exact; bins avg 1 element) ----
        for (int bb = tid; bb < NBIN; bb += 256) {
            int beg = (int)s_prefix[bb];
            int end = (int)s_prefix[bb + 1];
            for (int i2 = beg + 1; i2 < end; ++i2) {
                float key = s_sorted[i2];
                int jj = i2 - 1;
                while (jj >= beg && s_sorted[jj] > key) { s_sorted[jj + 1] = s_sorted[jj]; --jj; }
                s_sorted[jj + 1] = key;
            }
        }
        __syncthreads();                                   // (F)

        // ---- deviation bound D = max|ECDF chord - identity| (incl. extrapolation) ----
        float dev = fmaxf(fabsf((float)(tid + 1)   * inv_n - s_sorted[tid]),
                          fabsf((float)(tid + 257) * inv_n - s_sorted[tid + 256]));
        {   // endpoint extrapolation extrema (all threads, broadcast reads)
            float sa0 = s_sorted[0], sa1 = s_sorted[1];
            float sbA = s_sorted[510], sbB = s_sorted[511];
            float sl0 = inv_n * fast_rcp(sa1 - sa0);
            float slR = inv_n * fast_rcp(sbB - sbA);
            float lext = fabsf(inv_n - sl0 * sa0);
            float rext = fabsf(511.0f * inv_n + slR * (1.0f - sbA) - 1.0f);
            dev = fmaxf(dev, fmaxf(lext, rext));
        }
        #pragma unroll
        for (int o = 32; o > 0; o >>= 1) dev = fmaxf(dev, __shfl_down(dev, o, 64));
        if (lane == 0) s_wredf[wave] = dev;

        // ---- interval params (x0, slope): i = tid and tid+256 ----
        {
            float a = s_sorted[tid], b2 = s_sorted[tid + 1];
            s_params[tid] = make_float2(a, inv_n * fast_rcp(b2 - a));
            if (tid + 256 < NS - 1) {
                float c2 = s_sorted[tid + 256], d2 = s_sorted[tid + 257];
                s_params[tid + 256] = make_float2(c2, inv_n * fast_rcp(d2 - c2));
            }
        }
        __syncthreads();                                   // (F2) — last reads of pool phase 1

        float Dm = fmaxf(fmaxf(s_wredf[0], s_wredf[1]), fmaxf(s_wredf[2], s_wredf[3]));
        float D  = Dm + 1.5e-3f;                           // fp slop margin (> 1 grid step)

        float qlo = 0.0f - alpha;
        float qhi = 0.999f - alpha;
        int kmin = max(0,  (int)((qlo + 1.0f - D) * invstep) - 2);
        int kmax = min(NE, (int)((qhi + 1.0f + D) * invstep) + 3);
        kmax = min(kmax, kmin + WCAP);
        const int W = kmax - kmin;

        // ---- zero count bins (pool reused) + segment counters ----
        for (int e = tid; e < W; e += 256) s_cnt[e] = 0u;
        if (tid < 3) s_segcnt[tid] = 0u;
        __syncthreads();                                   // (G1)

        // ---- branch-free merge scatter: first grid index with rest >= x is closed-form ----
        #pragma unroll
        for (int sg = 0; sg < 3; ++sg) {
            int bmin = max(1000 * sg, kmin);
            int lim  = min(1000 * sg + 1000, kmax);
            if (bmin < lim) {                              // uniform branch
                float fs = (float)sg;
                int ci0 = (int)ceilf((v0 + fs) * invstep);
                int bi0 = max(ci0, bmin);
                if (bi0 < lim) { atomicAdd(&s_cnt[bi0 - kmin], 1u); atomicAdd(&s_segcnt[sg], 1u); }
                int ci1 = (int)ceilf((v1 + fs) * invstep);
                int bi1 = max(ci1, bmin);
                if (bi1 < lim) { atomicAdd(&s_cnt[bi1 - kmin], 1u); atomicAdd(&s_segcnt[sg], 1u); }
            }
        }
        __syncthreads();                                   // (G2)

        // ---- block inclusive scan over window counts (contiguous chunk / thread) ----
        const int c0 = (tid * W) >> 8;
        const int c1 = ((tid + 1) * W) >> 8;
        unsigned lsum = 0;
        #pragma unroll
        for (int e = 0; e < 8; ++e) { int idx = c0 + e; if (idx < c1) lsum += s_cnt[idx]; }
        unsigned sc = lsum;
        #pragma unroll
        for (int o = 1; o < 64; o <<= 1) {
            unsigned t2 = __shfl_up(sc, o, 64);
            if (lane >= o) sc += t2;
        }
        if (lane == 63) s_wredu[wave] = sc;
        __syncthreads();                                   // (G3)
        unsigned wbase = 0;
        for (int w = 0; w < 4; ++w) if (w < wave) wbase += s_wredu[w];
        unsigned run = wbase + sc - lsum;                  // exclusive prefix at c0
        const unsigned Bs1 = s_segcnt[0];
        const unsigned Bs2 = Bs1 + s_segcnt[1];

        // ---- fused scan pass 2 + ECDF fill (uniform control flow, pos in registers) ----
        #pragma unroll
        for (int e = 0; e < 8; ++e) {
            int idx = c0 + e;
            if (idx < c1) {
                run += s_cnt[idx];
                int k   = kmin + idx;
                int sgi = (k >= 1000) + (k >= 2000);
                unsigned Bv = (sgi == 0) ? 0u : ((sgi == 1) ? Bs1 : Bs2);
                int pos = (int)(run - Bv);
                int i = min(max(pos - 1, 0), NS - 2);
                float2 p = s_params[i];
                float fm = (float)(sgi - 1);
                float xn = -1.0f + (float)k * step;
                float r  = xn - fm;
                float y0 = (float)(i + 1) * inv_n;
                s_ecdfw[idx] = fm + (y0 + p.y * (r - p.x));
            }
        }
        __syncthreads();                                   // (G4)

        // ---- inverse CDF at 4 contiguous queries/thread (windowed search) ----
        if (j0 < NR) {
            float q = rj0 - alpha;
            int lo = 0, hi = W;
            while (lo < hi) {                               // bisect_left (uniform iter count)
                int mid = (lo + hi) >> 1;
                if (s_ecdfw[mid] < q) lo = mid + 1; else hi = mid;
            }
            int pos2 = lo;
            #pragma unroll
            for (int jj = 0; jj < 4; ++jj) {
                float rj = (jj == 0) ? rj0 : (jj == 1) ? rj1 : (jj == 2) ? rj2 : rj3;
                q = rj - alpha;
                if (jj > 0) while (pos2 < W && s_ecdfw[pos2] < q) ++pos2;
                int wi = min(max(pos2 - 1, 0), W - 2);
                float e0 = s_ecdfw[wi];
                float e1 = s_ecdfw[wi + 1];
                float slope = step * fast_rcp(e1 - e0);
                float xn0 = -1.0f + (float)(kmin + wi) * step;
                float res = xn0 + slope * (q - e0);
                float embv = res - rj;
                if (inp == 0) {
                    if (jj == 0) e1r0 = embv;
                    else if (jj == 1) e1r1 = embv;
                    else if (jj == 2) e1r2 = embv;
                    else e1r3 = embv;
                } else {
                    float ev = (jj == 0) ? e1r0 : (jj == 1) ? e1r1 : (jj == 2) ? e1r2 : e1r3;
                    float d = fabsf(embv - ev);
                    float c = fminf(d, 1.0f - d);
                    acc = fmaf(c, c, acc);
                }
            }
        }
        __syncthreads();                                   // (H) protect LDS before next input
    }

    // ---- block reduce acc, sqrt, write per-row ----
    #pragma unroll
    for (int o = 32; o > 0; o >>= 1) acc += __shfl_down(acc, o, 64);
    if (lane == 0) s_wredf[wave] = acc;
    __syncthreads();
    if (tid == 0) row_out[row] = sqrtf(s_wredf[0] + s_wredf[1] + s_wredf[2] + s_wredf[3]);
}

__global__ __launch_bounds__(256) void lcot_reduce_kernel(
    const float* __restrict__ row_vals, float* __restrict__ out)
{
    __shared__ float s_red[256];
    const int b = blockIdx.x;
    const int tid = threadIdx.x;
    float v = row_vals[b * NL + tid] + row_vals[b * NL + tid + 256];
    s_red[tid] = v;
    __syncthreads();
    for (int off = 128; off > 0; off >>= 1) {
        if (tid < off) s_red[tid] += s_red[tid + off];
        __syncthreads();
    }
    if (tid == 0) out[b] = s_red[0] * (1.0f / (float)NL);
}

extern "C" void kernel_launch(void* const* d_in, const int* in_sizes, int n_in,
                              void* d_out, int out_size, void* d_ws, size_t ws_size,
                              hipStream_t stream) {
    const float* x1  = (const float*)d_in[0];
    const float* x2  = (const float*)d_in[1];
    const float* ref = (const float*)d_in[2];
    float* out = (float*)d_out;
    float* row_vals = (float*)d_ws;   // NROWS floats of scratch

    lcot_row_kernel<<<NROWS, 256, 0, stream>>>(x1, x2, ref, row_vals);
    lcot_reduce_kernel<<<NB, 256, 0, stream>>>(row_vals, out);
}